// Round 5
// baseline (332.349 us; speedup 1.0000x reference)
//
#include <hip/hip_runtime.h>
#include <stdint.h>

// GCN 2-layer forward.
// prepw -> bin(bucket sort by dst-range, 1 read) -> histB(XCD-local) -> scan
//  -> scatB(XCD-local) -> gemm1(bf16 MFMA) -> spmm1 -> gemm2(fused relu+b1) -> spmm2+lsm

typedef __attribute__((ext_vector_type(8))) short short8;
typedef __attribute__((ext_vector_type(8))) unsigned short ushort8;
typedef __attribute__((ext_vector_type(4))) float f32x4;

#define NSLICE 8
#define BCHUNK 8192

// f32 -> bf16 bits (RNE)
static __device__ __forceinline__ uint32_t f2bu(float f) {
  uint32_t u = __float_as_uint(f);
  return (u + 0x7FFFu + ((u >> 16) & 1u)) >> 16;
}
static __device__ __forceinline__ float bu2f(unsigned short u) {
  return __uint_as_float(((uint32_t)u) << 16);
}

// ---------------- weight prep ----------------
__global__ __launch_bounds__(256) void prepw_k(const float* __restrict__ W1,
                                               const float* __restrict__ W2,
                                               short* __restrict__ W1bt,
                                               short* __restrict__ W2bt) {
  int i = blockIdx.x * 256 + threadIdx.x;
  if (i < 256 * 128) {
    int k = i >> 7, c = i & 127;
    W1bt[c * 256 + k] = (short)f2bu(W1[i]);
  }
  if (i < 128 * 64) {
    int k = i >> 6, c = i & 63;
    W2bt[c * 128 + k] = (short)f2bu(W2[i]);
  }
}

// ---------------- GEMM1: xwb[M,128](bf16) = X[M,256] @ W1 ----------------
__global__ __launch_bounds__(256) void gemm1_k(const float* __restrict__ X,
                                               const short* __restrict__ W1bt,
                                               unsigned short* __restrict__ Yb, int M) {
  __shared__ short As[128][72];   // 144B row stride = 16*9 -> conflict-free 16B ops
  const int tid = threadIdx.x;
  const int lane = tid & 63;
  const int wid = tid >> 6;
  const int wr = wid >> 1, wc = wid & 1;
  const int bm = blockIdx.x * 128;

  f32x4 acc[4][4];
#pragma unroll
  for (int i = 0; i < 4; ++i)
#pragma unroll
    for (int j = 0; j < 4; ++j) acc[i][j] = (f32x4)0.f;

  const int l15 = lane & 15;
  const int lk8 = (lane >> 4) * 8;

  for (int k0 = 0; k0 < 256; k0 += 64) {
#pragma unroll
    for (int i = 0; i < 8; ++i) {
      int idx = tid + i * 256;
      int r = idx >> 4;
      int kq = (idx & 15) << 2;
      int row = bm + r;
      float4 v = make_float4(0.f, 0.f, 0.f, 0.f);
      if (row < M) v = *(const float4*)&X[(size_t)row * 256 + k0 + kq];
      uint2 p;
      p.x = f2bu(v.x) | (f2bu(v.y) << 16);
      p.y = f2bu(v.z) | (f2bu(v.w) << 16);
      *(uint2*)&As[r][kq] = p;
    }
    __syncthreads();
#pragma unroll
    for (int kk = 0; kk < 64; kk += 32) {
      short8 a[4], b[4];
#pragma unroll
      for (int mi = 0; mi < 4; ++mi)
        a[mi] = *(const short8*)&As[wr * 64 + mi * 16 + l15][kk + lk8];
#pragma unroll
      for (int ni = 0; ni < 4; ++ni) {
        int bcol = wc * 64 + ni * 16 + l15;
        b[ni] = *(const short8*)&W1bt[bcol * 256 + k0 + kk + lk8];
      }
#pragma unroll
      for (int mi = 0; mi < 4; ++mi)
#pragma unroll
        for (int ni = 0; ni < 4; ++ni)
          acc[mi][ni] = __builtin_amdgcn_mfma_f32_16x16x32_bf16(a[mi], b[ni], acc[mi][ni], 0, 0, 0);
    }
    __syncthreads();
  }
#pragma unroll
  for (int mi = 0; mi < 4; ++mi) {
    int rbase = bm + wr * 64 + mi * 16 + (lane >> 4) * 4;
#pragma unroll
    for (int j = 0; j < 4; ++j) {
      int row = rbase + j;
      if (row < M) {
#pragma unroll
        for (int ni = 0; ni < 4; ++ni)
          Yb[(size_t)row * 128 + wc * 64 + ni * 16 + l15] =
              (unsigned short)f2bu(acc[mi][ni][j]);
      }
    }
  }
}

// -------- GEMM2: hwb[M,64](bf16) = relu(Hb+b1) @ W2 --------
__global__ __launch_bounds__(256) void gemm2_k(const unsigned short* __restrict__ Hb,
                                               const float* __restrict__ b1,
                                               const short* __restrict__ W2bt,
                                               unsigned short* __restrict__ Yb, int M) {
  __shared__ short As[128][72];
  const int tid = threadIdx.x;
  const int lane = tid & 63;
  const int wid = tid >> 6;
  const int bm = blockIdx.x * 128;

  f32x4 acc[2][4];
#pragma unroll
  for (int i = 0; i < 2; ++i)
#pragma unroll
    for (int j = 0; j < 4; ++j) acc[i][j] = (f32x4)0.f;

  const int l15 = lane & 15;
  const int lk8 = (lane >> 4) * 8;

  for (int k0 = 0; k0 < 128; k0 += 64) {
#pragma unroll
    for (int i = 0; i < 4; ++i) {
      int idx = tid + i * 256;
      int r = idx >> 3;
      int c8 = (idx & 7) * 8;
      int row = bm + r;
      uint4 p = make_uint4(0, 0, 0, 0);
      if (row < M) {
        ushort8 hv = *(const ushort8*)&Hb[(size_t)row * 128 + k0 + c8];
        float4 ba = *(const float4*)&b1[k0 + c8];
        float4 bb = *(const float4*)&b1[k0 + c8 + 4];
        float f0 = fmaxf(bu2f(hv[0]) + ba.x, 0.f);
        float f1 = fmaxf(bu2f(hv[1]) + ba.y, 0.f);
        float f2 = fmaxf(bu2f(hv[2]) + ba.z, 0.f);
        float f3 = fmaxf(bu2f(hv[3]) + ba.w, 0.f);
        float f4 = fmaxf(bu2f(hv[4]) + bb.x, 0.f);
        float f5 = fmaxf(bu2f(hv[5]) + bb.y, 0.f);
        float f6 = fmaxf(bu2f(hv[6]) + bb.z, 0.f);
        float f7 = fmaxf(bu2f(hv[7]) + bb.w, 0.f);
        p.x = f2bu(f0) | (f2bu(f1) << 16);
        p.y = f2bu(f2) | (f2bu(f3) << 16);
        p.z = f2bu(f4) | (f2bu(f5) << 16);
        p.w = f2bu(f6) | (f2bu(f7) << 16);
      }
      *(uint4*)&As[r][c8] = p;
    }
    __syncthreads();
#pragma unroll
    for (int kk = 0; kk < 64; kk += 32) {
      short8 a[2], b[4];
#pragma unroll
      for (int mi = 0; mi < 2; ++mi)
        a[mi] = *(const short8*)&As[wid * 32 + mi * 16 + l15][kk + lk8];
#pragma unroll
      for (int ni = 0; ni < 4; ++ni)
        b[ni] = *(const short8*)&W2bt[(ni * 16 + l15) * 128 + k0 + kk + lk8];
#pragma unroll
      for (int mi = 0; mi < 2; ++mi)
#pragma unroll
        for (int ni = 0; ni < 4; ++ni)
          acc[mi][ni] = __builtin_amdgcn_mfma_f32_16x16x32_bf16(a[mi], b[ni], acc[mi][ni], 0, 0, 0);
    }
    __syncthreads();
  }
#pragma unroll
  for (int mi = 0; mi < 2; ++mi) {
    int rbase = bm + wid * 32 + mi * 16 + (lane >> 4) * 4;
#pragma unroll
    for (int j = 0; j < 4; ++j) {
      int row = rbase + j;
      if (row < M) {
#pragma unroll
        for (int ni = 0; ni < 4; ++ni)
          Yb[(size_t)row * 64 + ni * 16 + l15] =
              (unsigned short)f2bu(acc[mi][ni][j]);
      }
    }
  }
}

// ---------------- Phase A: bucket-bin edges by dst range (single read) ----------------
// record: x = val bits, y = src | (dstlo << 17)   (src < 2^17, dstlo < 2^14)
__global__ __launch_bounds__(256) void bin_k(const int* __restrict__ src,
                                             const int* __restrict__ dst,
                                             const float* __restrict__ vals,
                                             int* __restrict__ bucket_cnt,
                                             int2* __restrict__ recs,
                                             int E, int NPS, int CAP) {
  __shared__ int cnt[NSLICE];
  __shared__ int base[NSLICE];
  const int tid = threadIdx.x;
  if (tid < NSLICE) cnt[tid] = 0;
  __syncthreads();
  int beg = blockIdx.x * BCHUNK;
  int end = min(beg + BCHUNK, E);
  for (int i = beg + tid; i < end; i += 256) {
    int b = dst[i] / NPS;
    atomicAdd(&cnt[b], 1);
  }
  __syncthreads();
  if (tid < NSLICE) {
    base[tid] = atomicAdd(&bucket_cnt[tid], cnt[tid]);
    cnt[tid] = 0;
  }
  __syncthreads();
  for (int i = beg + tid; i < end; i += 256) {
    int d = dst[i];
    int b = d / NPS;
    int pos = atomicAdd(&cnt[b], 1);
    int2 r;
    r.x = __float_as_int(vals[i]);
    r.y = src[i] | ((d - b * NPS) << 17);
    recs[(size_t)b * CAP + base[b] + pos] = r;
  }
}

// ---------------- Phase B1: per-bucket histogram (XCD-local atomics) ----------------
__global__ __launch_bounds__(256) void histb_k(const int2* __restrict__ recs,
                                               const int* __restrict__ bucket_cnt,
                                               int* __restrict__ deg, int NPS, int CAP) {
  int b = blockIdx.x & (NSLICE - 1);
  int chunk = blockIdx.x >> 3;
  int n = bucket_cnt[b];
  int beg = chunk * BCHUNK;
  int end = min(beg + BCHUNK, n);
  const int2* r = recs + (size_t)b * CAP;
  int dbase = b * NPS;
  for (int i = beg + threadIdx.x; i < end; i += 256)
    atomicAdd(&deg[dbase + (r[i].y >> 17)], 1);
}

// ---------------- scans ----------------
__global__ __launch_bounds__(256) void scan1_k(const int* __restrict__ deg,
                                               int* __restrict__ rowptr,
                                               int* __restrict__ partial, int M) {
  __shared__ int sh[256];
  int tid = threadIdx.x;
  int i = blockIdx.x * 256 + tid;
  int v = (i < M) ? deg[i] : 0;
  sh[tid] = v;
  __syncthreads();
#pragma unroll
  for (int o = 1; o < 256; o <<= 1) {
    int t = (tid >= o) ? sh[tid - o] : 0;
    __syncthreads();
    sh[tid] += t;
    __syncthreads();
  }
  if (i < M) rowptr[i] = sh[tid] - v;
  if (tid == 255) partial[blockIdx.x] = sh[255];
}

__global__ __launch_bounds__(512) void scan2_k(int* __restrict__ partial, int NB) {
  __shared__ int sh[512];
  int tid = threadIdx.x;
  int v = (tid < NB) ? partial[tid] : 0;
  sh[tid] = v;
  __syncthreads();
#pragma unroll
  for (int o = 1; o < 512; o <<= 1) {
    int t = (tid >= o) ? sh[tid - o] : 0;
    __syncthreads();
    sh[tid] += t;
    __syncthreads();
  }
  if (tid < NB) partial[tid] = sh[tid] - v;
}

__global__ __launch_bounds__(256) void scan3_k(int* __restrict__ rowptr,
                                               const int* __restrict__ partial,
                                               int* __restrict__ cursor, int M, int E) {
  int i = blockIdx.x * 256 + threadIdx.x;
  if (i < M) {
    int r = rowptr[i] + partial[i >> 8];
    rowptr[i] = r;
    cursor[i] = r;
    if (i == 0) rowptr[M] = E;
  }
}

// ---------------- Phase B2: per-bucket scatter into CSR (XCD-local) ----------------
__global__ __launch_bounds__(256) void scatb_k(const int2* __restrict__ recs,
                                               const int* __restrict__ bucket_cnt,
                                               int* __restrict__ cursor,
                                               int2* __restrict__ edges,
                                               int NPS, int CAP) {
  int b = blockIdx.x & (NSLICE - 1);
  int chunk = blockIdx.x >> 3;
  int n = bucket_cnt[b];
  int beg = chunk * BCHUNK;
  int end = min(beg + BCHUNK, n);
  const int2* r = recs + (size_t)b * CAP;
  int dbase = b * NPS;
  for (int i = beg + threadIdx.x; i < end; i += 256) {
    int2 rec = r[i];
    int d = dbase + (rec.y >> 17);
    int pos = atomicAdd(&cursor[d], 1);
    int2 e;
    e.x = rec.y & 0x1FFFF;
    e.y = rec.x;
    edges[pos] = e;
  }
}

// ---------------- SpMM1: haccb[M,128](bf16) = A @ xwb, 16 thr/node ----------------
__global__ __launch_bounds__(256) void spmm1_k(const int* __restrict__ rowptr,
                                               const int2* __restrict__ edges,
                                               const unsigned short* __restrict__ Xb,
                                               unsigned short* __restrict__ outb, int M) {
  int node = blockIdx.x * 16 + (threadIdx.x >> 4);
  int g = (threadIdx.x & 15) * 8;
  if (node >= M) return;
  int e = rowptr[node];
  const int end = rowptr[node + 1];
  float a0[8], a1[8];
#pragma unroll
  for (int j = 0; j < 8; ++j) { a0[j] = 0.f; a1[j] = 0.f; }
  for (; e + 4 <= end; e += 4) {
    int2 e0 = edges[e], e1 = edges[e + 1], e2 = edges[e + 2], e3 = edges[e + 3];
    float v0 = __int_as_float(e0.y), v1 = __int_as_float(e1.y);
    float v2 = __int_as_float(e2.y), v3 = __int_as_float(e3.y);
    ushort8 x0 = *(const ushort8*)&Xb[(size_t)e0.x * 128 + g];
    ushort8 x1 = *(const ushort8*)&Xb[(size_t)e1.x * 128 + g];
    ushort8 x2 = *(const ushort8*)&Xb[(size_t)e2.x * 128 + g];
    ushort8 x3 = *(const ushort8*)&Xb[(size_t)e3.x * 128 + g];
#pragma unroll
    for (int j = 0; j < 8; ++j) {
      a0[j] = fmaf(v0, bu2f(x0[j]), a0[j]);
      a1[j] = fmaf(v1, bu2f(x1[j]), a1[j]);
      a0[j] = fmaf(v2, bu2f(x2[j]), a0[j]);
      a1[j] = fmaf(v3, bu2f(x3[j]), a1[j]);
    }
  }
  for (; e < end; ++e) {
    int2 e0 = edges[e];
    float v0 = __int_as_float(e0.y);
    ushort8 x0 = *(const ushort8*)&Xb[(size_t)e0.x * 128 + g];
#pragma unroll
    for (int j = 0; j < 8; ++j) a0[j] = fmaf(v0, bu2f(x0[j]), a0[j]);
  }
  ushort8 o;
#pragma unroll
  for (int j = 0; j < 8; ++j) o[j] = (unsigned short)f2bu(a0[j] + a1[j]);
  *(ushort8*)&outb[(size_t)node * 128 + g] = o;
}

// ---------------- SpMM2 + bias + log_softmax fused, 8 thr/node ----------------
__global__ __launch_bounds__(256) void spmm2_lsm_k(const int* __restrict__ rowptr,
                                                   const int2* __restrict__ edges,
                                                   const unsigned short* __restrict__ Hb,
                                                   const float* __restrict__ b2,
                                                   float* __restrict__ out, int M) {
  int node = blockIdx.x * 32 + (threadIdx.x >> 3);
  int g = (threadIdx.x & 7) * 8;
  if (node >= M) return;
  int e = rowptr[node];
  const int end = rowptr[node + 1];
  float a0[8], a1[8];
#pragma unroll
  for (int j = 0; j < 8; ++j) { a0[j] = 0.f; a1[j] = 0.f; }
  for (; e + 4 <= end; e += 4) {
    int2 e0 = edges[e], e1 = edges[e + 1], e2 = edges[e + 2], e3 = edges[e + 3];
    float v0 = __int_as_float(e0.y), v1 = __int_as_float(e1.y);
    float v2 = __int_as_float(e2.y), v3 = __int_as_float(e3.y);
    ushort8 x0 = *(const ushort8*)&Hb[(size_t)e0.x * 64 + g];
    ushort8 x1 = *(const ushort8*)&Hb[(size_t)e1.x * 64 + g];
    ushort8 x2 = *(const ushort8*)&Hb[(size_t)e2.x * 64 + g];
    ushort8 x3 = *(const ushort8*)&Hb[(size_t)e3.x * 64 + g];
#pragma unroll
    for (int j = 0; j < 8; ++j) {
      a0[j] = fmaf(v0, bu2f(x0[j]), a0[j]);
      a1[j] = fmaf(v1, bu2f(x1[j]), a1[j]);
      a0[j] = fmaf(v2, bu2f(x2[j]), a0[j]);
      a1[j] = fmaf(v3, bu2f(x3[j]), a1[j]);
    }
  }
  for (; e < end; ++e) {
    int2 e0 = edges[e];
    float v0 = __int_as_float(e0.y);
    ushort8 x0 = *(const ushort8*)&Hb[(size_t)e0.x * 64 + g];
#pragma unroll
    for (int j = 0; j < 8; ++j) a0[j] = fmaf(v0, bu2f(x0[j]), a0[j]);
  }
  float v[8];
  float4 ba = *(const float4*)&b2[g];
  float4 bb = *(const float4*)&b2[g + 4];
  v[0] = a0[0] + a1[0] + ba.x; v[1] = a0[1] + a1[1] + ba.y;
  v[2] = a0[2] + a1[2] + ba.z; v[3] = a0[3] + a1[3] + ba.w;
  v[4] = a0[4] + a1[4] + bb.x; v[5] = a0[5] + a1[5] + bb.y;
  v[6] = a0[6] + a1[6] + bb.z; v[7] = a0[7] + a1[7] + bb.w;
  float m = v[0];
#pragma unroll
  for (int j = 1; j < 8; ++j) m = fmaxf(m, v[j]);
#pragma unroll
  for (int o = 1; o < 8; o <<= 1) m = fmaxf(m, __shfl_xor(m, o, 64));
  float s = 0.f;
#pragma unroll
  for (int j = 0; j < 8; ++j) s += expf(v[j] - m);
#pragma unroll
  for (int o = 1; o < 8; o <<= 1) s += __shfl_xor(s, o, 64);
  float lse = m + logf(s);
  float4 r0 = make_float4(v[0] - lse, v[1] - lse, v[2] - lse, v[3] - lse);
  float4 r1 = make_float4(v[4] - lse, v[5] - lse, v[6] - lse, v[7] - lse);
  *(float4*)&out[(size_t)node * 64 + g] = r0;
  *(float4*)&out[(size_t)node * 64 + g + 4] = r1;
}

extern "C" void kernel_launch(void* const* d_in, const int* in_sizes, int n_in,
                              void* d_out, int out_size, void* d_ws, size_t ws_size,
                              hipStream_t stream) {
  const float* x    = (const float*)d_in[0];
  const int*   src  = (const int*)  d_in[1];
  const int*   dst  = (const int*)  d_in[2];
  const float* vals = (const float*)d_in[3];
  const float* W1   = (const float*)d_in[4];
  const float* b1   = (const float*)d_in[5];
  const float* W2   = (const float*)d_in[6];
  const float* b2   = (const float*)d_in[7];
  const int M = in_sizes[0] / 256;   // 100000
  const int E = in_sizes[1];         // 1600000

  const int NPS = (M + NSLICE - 1) / NSLICE;      // 12500
  const int CAP = E / NSLICE + 8192;              // 208192 per bucket (>>11 sigma margin)

  // workspace layout
  int2* edges = (int2*)d_ws;                                 // E*8B
  int2* recs  = edges + E;                                   // NSLICE*CAP*8B
  unsigned short* xwb   = (unsigned short*)(recs + (size_t)NSLICE * CAP); // M*128 bf16
  unsigned short* haccb = xwb + (size_t)M * 128;             // M*128 bf16
  unsigned short* hwb   = haccb + (size_t)M * 128;           // M*64 bf16
  int* deg    = (int*)(hwb + (size_t)M * 64);                // M
  int* bucket_cnt = deg + M;                                 // NSLICE
  int* rowptr = bucket_cnt + NSLICE;                         // M+1
  int* cursor = rowptr + M + 1;                              // M
  int* partial = cursor + M;                                 // 512
  short* W1bt = (short*)(partial + 512);                     // 256*128
  short* W2bt = W1bt + 256 * 128;                            // 128*64
  float* outf = (float*)d_out;

  const int NB  = (M + 255) / 256;
  const int gb  = (M + 127) / 128;
  const int gbin = (E + BCHUNK - 1) / BCHUNK;                    // 196
  const int gbkt = NSLICE * ((CAP + BCHUNK - 1) / BCHUNK);       // 8*26

  // --- CSR build + weight prep ---
  hipMemsetAsync(deg, 0, (size_t)(M + NSLICE) * sizeof(int), stream);  // deg + bucket_cnt
  prepw_k<<<128, 256, 0, stream>>>(W1, W2, W1bt, W2bt);
  bin_k<<<gbin, 256, 0, stream>>>(src, dst, vals, bucket_cnt, recs, E, NPS, CAP);
  histb_k<<<gbkt, 256, 0, stream>>>(recs, bucket_cnt, deg, NPS, CAP);
  scan1_k<<<NB, 256, 0, stream>>>(deg, rowptr, partial, M);
  scan2_k<<<1, 512, 0, stream>>>(partial, NB);
  scan3_k<<<NB, 256, 0, stream>>>(rowptr, partial, cursor, M, E);
  scatb_k<<<gbkt, 256, 0, stream>>>(recs, bucket_cnt, cursor, edges, NPS, CAP);

  // --- layer 1 ---
  gemm1_k<<<gb, 256, 0, stream>>>(x, W1bt, xwb, M);
  spmm1_k<<<(M + 15) / 16, 256, 0, stream>>>(rowptr, edges, xwb, haccb, M);

  // --- layer 2 + fused log_softmax ---
  gemm2_k<<<gb, 256, 0, stream>>>(haccb, b1, W2bt, hwb, M);
  spmm2_lsm_k<<<(M + 31) / 32, 256, 0, stream>>>(rowptr, edges, hwb, b2, outf, M);
}